// Round 1
// 251.302 us; speedup vs baseline: 1.0083x; 1.0083x over previous
//
#include <hip/hip_runtime.h>

// x [B=8, C=2, D=16, T=128000] fp32, x_wave [B=8, D=16, T=128000] fp32,
// pad_left = pad_right = 8, WINDOW=8, L=16, k=2.
//
// Identity (same as previous kernel): output position p = seg*8 + d gets
//   x[b,c,d,seg]*w[b,d,seg] + x[b,c,d+8,seg-1]*w[b,d+8,seg-1]
// Valid segs: 1..T-1 (pad trimming removes seg 0 head and seg T tail).
//
// Restructure vs previous version (48 scalar dword loads/thread, 1.93 TB/s):
//  Phase 1: block stages PRODUCTS x*w for a 256-seg tile into LDS.
//    - float4 loads along t (16B/lane, 1KB/wave/instr), 12/thread, unrolled
//      -> ~12KB in flight per wave (vs ~2.5KB before), breaks the
//         512000B-stride channel aliasing of 48 concurrent scalar streams.
//    - w loaded ONCE per element, reused in-register for c=0 and c=1.
//    - ds_write_b128, lanes hit consecutive 16B slots: conflict-free.
//  Phase 2: gather 8 terms per output float4 from LDS (scalar ds_reads,
//    2-way bank aliasing = free on CDNA4) and store fully contiguous float4s
//    (consecutive lanes -> consecutive 16B).
// LDS 33,280 B/block -> 4 blocks/CU (133KB of 160KB), 16 waves/CU.

constexpr int B = 8;
constexpr int C = 2;
constexpr int D = 16;
constexpr int T = 128000;

constexpr int SEGS  = 256;        // segs per block; T/SEGS = 500 exactly
constexpr int PITCH = 260;        // floats per LDS row: t in [s0-4, s0+256); 1040B = 16B-multiple
constexpr int NBLK  = T / SEGS;   // 500

__global__ __launch_bounds__(256, 4) void oaa_lds_kernel(
    const float* __restrict__ x,
    const float* __restrict__ xw,
    float* __restrict__ out,
    int S)
{
    __shared__ float P[C][D][PITCH];   // products x*w; tloc = t - (s0-4)

    const int j  = threadIdx.x;
    const int b  = blockIdx.y;
    const int s0 = blockIdx.x * SEGS;

    const float* __restrict__ xwb = xw + (size_t)b * D * T;
    const float* __restrict__ xb0 = x  + (size_t)b * C * D * T;   // c=0
    const float* __restrict__ xb1 = xb0 + (size_t)D * T;          // c=1

    // ---- Phase 1: load + multiply + transposed stage ----
    // Main: 16 d-rows x 64 float4 covering t in [s0, s0+256): 1024 tasks / 256 thr.
#pragma unroll
    for (int i = 0; i < 4; ++i) {
        const int tau = j + 256 * i;
        const int d   = tau >> 6;                  // 0..15 (wave-uniform)
        const int col = tau & 63;                  // = lane: contiguous 1KB per wave
        const size_t g = (size_t)d * T + (size_t)(s0 + 4 * col);
        const float4 wv  = *(const float4*)(xwb + g);
        const float4 xv0 = *(const float4*)(xb0 + g);
        const float4 xv1 = *(const float4*)(xb1 + g);
        *(float4*)&P[0][d][4 + 4 * col] =
            make_float4(xv0.x * wv.x, xv0.y * wv.y, xv0.z * wv.z, xv0.w * wv.w);
        *(float4*)&P[1][d][4 + 4 * col] =
            make_float4(xv1.x * wv.x, xv1.y * wv.y, xv1.z * wv.z, xv1.w * wv.w);
    }
    // Halo: one float4 at t = s0-4 for d in [8,16) (only tloc=3, i.e. t=s0-1,
    // is ever read — by seg s0's second term). Block 0 clamps to t=0; its halo
    // is only reachable from seg 0, which is masked at store time.
    if (j < 8) {
        const int d  = j + 8;
        const int th = (s0 >= 4) ? (s0 - 4) : 0;
        const size_t g = (size_t)d * T + (size_t)th;
        const float4 wv  = *(const float4*)(xwb + g);
        const float4 xv0 = *(const float4*)(xb0 + g);
        const float4 xv1 = *(const float4*)(xb1 + g);
        *(float4*)&P[0][d][0] =
            make_float4(xv0.x * wv.x, xv0.y * wv.y, xv0.z * wv.z, xv0.w * wv.w);
        *(float4*)&P[1][d][0] =
            make_float4(xv1.x * wv.x, xv1.y * wv.y, xv1.z * wv.z, xv1.w * wv.w);
    }
    __syncthreads();

    // ---- Phase 2: gather + contiguous store ----
    // 256 segs x 2 c x 2 halves = 1024 float4 stores / 256 thr.
    // Lane order (half fastest, then seg) -> consecutive lanes store
    // consecutive 16B: fully coalesced 1KB/wave store instructions.
    const size_t ob = (size_t)b * C * S;
#pragma unroll
    for (int i = 0; i < 4; ++i) {
        const int sig  = j + 256 * i;              // 0..1023
        const int half = sig & 1;
        const int sloc = (sig >> 1) & (SEGS - 1);
        const int c    = sig >> 9;                 // wave-uniform
        const int seg  = s0 + sloc;
        if (seg != 0) {                            // only block 0 / seg 0 masked
            const int dbase = 4 * half;
            const int ta = sloc + 4;               // term0: t = seg
            const int tb = sloc + 3;               // term1: t = seg-1
            float4 o;
            o.x = P[c][dbase + 0][ta] + P[c][dbase +  8][tb];
            o.y = P[c][dbase + 1][ta] + P[c][dbase +  9][tb];
            o.z = P[c][dbase + 2][ta] + P[c][dbase + 10][tb];
            o.w = P[c][dbase + 3][ta] + P[c][dbase + 11][tb];
            *(float4*)(out + ob + (size_t)c * S + (size_t)seg * 8 - 8 + dbase) = o;
        }
    }
}

extern "C" void kernel_launch(void* const* d_in, const int* in_sizes, int n_in,
                              void* d_out, int out_size, void* d_ws, size_t ws_size,
                              hipStream_t stream) {
    const float* x  = (const float*)d_in[0];
    const float* xw = (const float*)d_in[1];
    float* out = (float*)d_out;

    const int S = out_size / (B * C);              // 1023992 floats per (b,c)
    dim3 grid(NBLK, B);                            // 500 x 8
    oaa_lds_kernel<<<grid, dim3(256), 0, stream>>>(x, xw, out, S);
}